// Round 10
// baseline (1630.754 us; speedup 1.0000x reference)
//
#include <hip/hip_runtime.h>
#include <math.h>

#define HIDDEN 100
#define HEADS 8
#define D 800          // HIDDEN*HEADS
#define ALPHA 0.2f

typedef unsigned short ushort;
typedef unsigned int uint;
typedef __attribute__((ext_vector_type(8))) short bf16x8;
typedef __attribute__((ext_vector_type(4))) float f32x4;

__device__ inline float bf2f(ushort u) { uint x = ((uint)u) << 16; return __uint_as_float(x); }
__device__ inline ushort f2bf(float f) {
    uint u = __float_as_uint(f);
    u += 0x7FFF + ((u >> 16) & 1);   // round-to-nearest-even
    return (ushort)(u >> 16);
}

// async global->LDS, 16B per lane; LDS dest must be the WAVE-UNIFORM base (HW adds lane*16)
__device__ inline void gl_lds16(const void* g, void* l) {
    __builtin_amdgcn_global_load_lds((const __attribute__((address_space(1))) void*)g,
                                     (__attribute__((address_space(3))) void*)l, 16, 0, 0);
}

// ---------- CSR row_ptr from sorted src via binary search ----------
__global__ void k_rowptr(const int* __restrict__ src, int E, int n, int* __restrict__ row_ptr) {
    int i = blockIdx.x * blockDim.x + threadIdx.x;
    if (i > n) return;
    int lo = 0, hi = E;
    while (lo < hi) { int mid = (lo + hi) >> 1; if (src[mid] < i) lo = mid + 1; else hi = mid; }
    row_ptr[i] = lo;
}

// ---------- repack kernels (3,8,800,100) -> per-layer transposed bf16 (hi plane only) ----------
// Bsp layout: [layer][n=800][k=800] bf16, Bt[n][k] = kin[l, n/100, k, n%100]
__global__ void k_repack(const float* __restrict__ kin, ushort* __restrict__ bsp) {
    int gid = blockIdx.x * blockDim.x + threadIdx.x;
    if (gid >= 3 * D * D) return;
    int l = gid / (D * D);
    int rem = gid % (D * D);
    int nn = rem / D;        // output col (n)
    int k = rem % D;         // output row in k
    int h = nn / HIDDEN, c = nn % HIDDEN;
    float v = kin[((size_t)(l * HEADS + h) * D + k) * HIDDEN + c];
    bsp[((size_t)l * D + nn) * D + k] = f2bf(v);
}

// ---------- x = relu(ns @ W_pre + b_pre), K=32; output split bf16 planes ----------
__global__ __launch_bounds__(256) void k_pre(const float* __restrict__ ns, const float* __restrict__ W,
                                             const float* __restrict__ b, ushort* __restrict__ xh,
                                             ushort* __restrict__ xl, int n) {
    int j = blockIdx.x * 256 + threadIdx.x;
    if (j >= D) return;
    float wk[32];
#pragma unroll
    for (int k = 0; k < 32; k++) wk[k] = W[k * D + j];
    float bj = b[j];
    int r0 = blockIdx.y * 32;
    int r1 = min(r0 + 32, n);
    for (int r = r0; r < r1; r++) {
        float acc = bj;
#pragma unroll
        for (int k = 0; k < 32; k++) acc += ns[r * 32 + k] * wk[k];
        acc = fmaxf(acc, 0.f);
        ushort h = f2bf(acc);
        xh[(size_t)r * D + j] = h;
        xl[(size_t)r * D + j] = f2bf(acc - bf2f(h));
    }
}

// ---------- Ht[M x 800](bf16) = (xh+xl)[M x 800] @ Bh[800 x 800], MFMA 2-pass compensated ----------
// BM=128 BN=160 BK=32; 4 waves (2x2); dbuf LDS 52KB (3 blocks/CU); all staging via
// global_load_lds; counted-vmcnt pipeline; XCD-aware block swizzle.
// FUSED s/t epilogue: s[i,h] += sum_c acc*As, t likewise (shfl-reduce + atomicAdd).
__global__ __launch_bounds__(256) void k_gemm(const ushort* __restrict__ xh, const ushort* __restrict__ xl,
                                              const ushort* __restrict__ Bsp, const float* __restrict__ att_l,
                                              ushort* __restrict__ C, float* __restrict__ s_all,
                                              float* __restrict__ t_all, int M) {
    // fragment-ordered tiles: 512 ushorts (1024B) per 16x32 tile, linear in lane*16B
    __shared__ __align__(16) ushort Af[2][16 * 512];   // tiles 0..7 hi, 8..15 lo (32 KB)
    __shared__ __align__(16) ushort Bf[2][10 * 512];   // tiles 0..9 (B hi only, 20 KB)

    int d = blockIdx.x;
    int q = d & 7, m = d >> 3;      // XCD swizzle: same row-block -> same XCD
    int c = m % 5, j = m / 5;
    int r = j * 8 + q;
    int nrb = (M + 127) >> 7;
    if (r >= nrb) return;
    int row0 = r * 128, col0 = c * 160;

    int t = threadIdx.x;
    int w = t >> 6, lane = t & 63;
    int wr = w >> 1, wc = w & 1;
    int l15 = lane & 15, ks = lane >> 4;

    // staging: per wave 4 A-tiles + {2,2,3,3} B-tiles
    const ushort* srcA[4];
    int ldsA[4];
#pragma unroll
    for (int i = 0; i < 4; i++) {
        int g = i * 4 + w;          // 0..15
        int mat = g >> 3, tile = g & 7;
        int row = min(row0 + tile * 16 + l15, M - 1);
        srcA[i] = (mat ? xl : xh) + (size_t)row * D + ks * 8;
        ldsA[i] = g * 512;
    }
    int bcnt = (w < 2) ? 2 : 3;
    int bbase = (w < 2) ? 2 * w : 4 + 3 * (w - 2);   // wave0:{0,1} wave1:{2,3} wave2:{4,5,6} wave3:{7,8,9}
    const ushort* srcB[3];
    int ldsB[3];
#pragma unroll
    for (int i = 0; i < 3; i++) {
        int tile = bbase + i;
        if (tile > 9) tile = 9;
        int col = col0 + tile * 16 + l15;
        srcB[i] = Bsp + (size_t)col * D + ks * 8;
        ldsB[i] = tile * 512;
    }

    f32x4 acc[4][5] = {};

    auto stage = [&](int buf, int k0) {
#pragma unroll
        for (int i = 0; i < 4; i++) gl_lds16(srcA[i] + k0, &Af[buf][ldsA[i]]);
        for (int i = 0; i < bcnt; i++) gl_lds16(srcB[i] + k0, &Bf[buf][ldsB[i]]);
    };
    auto compute = [&](int buf) {
        bf16x8 bh[5];
#pragma unroll
        for (int ni = 0; ni < 5; ni++)
            bh[ni] = *(const bf16x8*)&Bf[buf][(wc * 5 + ni) * 512 + lane * 8];
#pragma unroll
        for (int mi = 0; mi < 4; mi++) {
            int tA = wr * 4 + mi;
            bf16x8 ah = *(const bf16x8*)&Af[buf][tA * 512 + lane * 8];
            bf16x8 al = *(const bf16x8*)&Af[buf][(8 + tA) * 512 + lane * 8];
#pragma unroll
            for (int ni = 0; ni < 5; ni++) {
                acc[mi][ni] = __builtin_amdgcn_mfma_f32_16x16x32_bf16(ah, bh[ni], acc[mi][ni], 0, 0, 0);
                acc[mi][ni] = __builtin_amdgcn_mfma_f32_16x16x32_bf16(al, bh[ni], acc[mi][ni], 0, 0, 0);
            }
        }
    };

    stage(0, 0);                               // S_0 in flight (6/7 per wave)
    for (int kt = 0; kt < 25; kt++) {
        if (kt < 24) {
            stage((kt + 1) & 1, (kt + 1) * 32);   // S_{t+1} stays in flight across the barrier
            if (w < 2) asm volatile("s_waitcnt vmcnt(6)" ::: "memory");
            else       asm volatile("s_waitcnt vmcnt(7)" ::: "memory");
        } else {
            asm volatile("s_waitcnt vmcnt(0)" ::: "memory");
        }
        __builtin_amdgcn_s_barrier();          // all waves' S_t landed (raw barrier, no drain)
        compute(kt & 1);
        __builtin_amdgcn_s_barrier();          // all waves done reading buf before re-stage
    }

    // C/D layout: col = lane&15, row = (lane>>4)*4 + reg   [m89-verified]
#pragma unroll
    for (int mi = 0; mi < 4; mi++) {
#pragma unroll
        for (int ni = 0; ni < 5; ni++) {
            int gr0 = row0 + wr * 64 + mi * 16 + ks * 4;
            int gc = col0 + wc * 80 + ni * 16 + l15;
#pragma unroll
            for (int rr = 0; rr < 4; rr++) {
                int gr = gr0 + rr;
                if (gr < M) C[(size_t)gr * D + gc] = f2bf(acc[mi][ni][rr]);
            }
        }
    }

    // ---- fused s/t epilogue: wave cols W0..W0+79 span <= 2 heads ----
    int W0 = col0 + wc * 80;
    int hb = W0 / 100;
    bool span = (W0 % 100) > 20;               // 80 cols cross a head boundary iff W0%100 > 20
#pragma unroll
    for (int mi = 0; mi < 4; mi++) {
        float ps0[4] = {}, ps1[4] = {}, pt0[4] = {}, pt1[4] = {};
#pragma unroll
        for (int ni = 0; ni < 5; ni++) {
            int gc = W0 + ni * 16 + l15;
            int hd = gc / 100, cc = gc - hd * 100;
            int idx = hd - hb;                 // 0 or 1
            float as = att_l[hd * 200 + cc];
            float at = att_l[hd * 200 + 100 + cc];
#pragma unroll
            for (int rr = 0; rr < 4; rr++) {
                float v = acc[mi][ni][rr];
                ps0[rr] += (idx == 0) ? v * as : 0.f;
                ps1[rr] += (idx == 1) ? v * as : 0.f;
                pt0[rr] += (idx == 0) ? v * at : 0.f;
                pt1[rr] += (idx == 1) ? v * at : 0.f;
            }
        }
#pragma unroll
        for (int o = 1; o < 16; o <<= 1) {
#pragma unroll
            for (int rr = 0; rr < 4; rr++) {
                ps0[rr] += __shfl_xor(ps0[rr], o);
                ps1[rr] += __shfl_xor(ps1[rr], o);
                pt0[rr] += __shfl_xor(pt0[rr], o);
                pt1[rr] += __shfl_xor(pt1[rr], o);
            }
        }
        if (l15 == 0) {
#pragma unroll
            for (int rr = 0; rr < 4; rr++) {
                int gr = row0 + wr * 64 + mi * 16 + ks * 4 + rr;
                if (gr < M) {
                    atomicAdd(&s_all[gr * 8 + hb], ps0[rr]);
                    atomicAdd(&t_all[gr * 8 + hb], pt0[rr]);
                    if (span) {
                        atomicAdd(&s_all[gr * 8 + hb + 1], ps1[rr]);
                        atomicAdd(&t_all[gr * 8 + hb + 1], pt1[rr]);
                    }
                }
            }
        }
    }
}

// ---------- per-node segment softmax + aggregate + relu + residual (x planes in-place) ----------
__global__ __launch_bounds__(256) void k_edge(const ushort* __restrict__ Ht, ushort* __restrict__ xh,
                                              ushort* __restrict__ xl,
                                              const float* __restrict__ s_all, const float* __restrict__ t_all,
                                              const int* __restrict__ dst, const int* __restrict__ row_ptr,
                                              int n) {
    int i = blockIdx.x;
    int t = threadIdx.x;
    __shared__ float lw[32][8];
    __shared__ int ld[32];
    int e0 = row_ptr[i], e1 = row_ptr[i + 1];
    int h = t / 25;            // head for aggregation (valid for t<200)
    int el = t >> 3, hh = t & 7;
    float s_ih = s_all[i * 8 + hh];
    float acc0 = 0, acc1 = 0, acc2 = 0, acc3 = 0, den = 0;

    for (int base = e0; base < e1; base += 32) {
        int cnt = min(32, e1 - base);
        __syncthreads();
        if (el < cnt) {
            int dd = dst[base + el];
            float ev = s_ih + t_all[dd * 8 + hh];
            ev = ev >= 0.f ? ev : ALPHA * ev;
            ev = fminf(fmaxf(ev, -2.f), 2.f);
            lw[el][hh] = __expf(ev);
            if (hh == 0) ld[el] = dd;
        }
        __syncthreads();
        if (t < 200) {
#pragma unroll 4
            for (int e = 0; e < cnt; e++) {
                int dd = ld[e];
                uint2 v = *(const uint2*)(Ht + (size_t)dd * D + t * 4);
                float wgt = lw[e][h];
                acc0 += wgt * bf2f((ushort)(v.x & 0xFFFF));
                acc1 += wgt * bf2f((ushort)(v.x >> 16));
                acc2 += wgt * bf2f((ushort)(v.y & 0xFFFF));
                acc3 += wgt * bf2f((ushort)(v.y >> 16));
                den += wgt;
            }
        }
    }
    if (t < 200) {
        size_t off = (size_t)i * D + t * 4;
        uint2 vh = *(uint2*)(xh + off);
        uint2 vl = *(uint2*)(xl + off);
        float x0 = bf2f((ushort)(vh.x & 0xFFFF)) + bf2f((ushort)(vl.x & 0xFFFF));
        float x1 = bf2f((ushort)(vh.x >> 16))    + bf2f((ushort)(vl.x >> 16));
        float x2 = bf2f((ushort)(vh.y & 0xFFFF)) + bf2f((ushort)(vl.y & 0xFFFF));
        float x3 = bf2f((ushort)(vh.y >> 16))    + bf2f((ushort)(vl.y >> 16));
        float inv = den > 0.f ? 1.f / den : 0.f;
        x0 += fmaxf(acc0 * inv, 0.f);
        x1 += fmaxf(acc1 * inv, 0.f);
        x2 += fmaxf(acc2 * inv, 0.f);
        x3 += fmaxf(acc3 * inv, 0.f);
        ushort h0 = f2bf(x0), h1 = f2bf(x1), h2 = f2bf(x2), h3 = f2bf(x3);
        ushort l0 = f2bf(x0 - bf2f(h0)), l1 = f2bf(x1 - bf2f(h1));
        ushort l2 = f2bf(x2 - bf2f(h2)), l3 = f2bf(x3 - bf2f(h3));
        *(uint2*)(xh + off) = make_uint2((uint)h0 | ((uint)h1 << 16), (uint)h2 | ((uint)h3 << 16));
        *(uint2*)(xl + off) = make_uint2((uint)l0 | ((uint)l1 << 16), (uint)l2 | ((uint)l3 << 16));
    }
}

// ---------- final stage A: per-block partial of sum_i (x_i . Wl + bl) * Wc_i ----------
__global__ __launch_bounds__(256) void k_final(const ushort* __restrict__ xh, const ushort* __restrict__ xl,
                                               const float* __restrict__ Wl, const float* __restrict__ bl,
                                               const float* __restrict__ Wc, float* __restrict__ fpart, int n) {
    __shared__ float part[4];
    int lane = threadIdx.x & 63, w = threadIdx.x >> 6;
    int wid = blockIdx.x * 4 + w;
    int nw = gridDim.x * 4;
    float p = 0.f;
    for (int i = wid; i < n; i += nw) {
        float dot = 0.f;
#pragma unroll
        for (int r = 0; r < 13; r++) {
            int j = r * 64 + lane;
            if (j < D) {
                size_t off = (size_t)i * D + j;
                dot += (bf2f(xh[off]) + bf2f(xl[off])) * Wl[j];
            }
        }
#pragma unroll
        for (int off = 32; off; off >>= 1) dot += __shfl_xor(dot, off);
        if (lane == 0) p += (dot + bl[0]) * Wc[i];
    }
    if (lane == 0) part[w] = p;
    __syncthreads();
    if (threadIdx.x == 0) fpart[blockIdx.x] = part[0] + part[1] + part[2] + part[3];
}

// ---------- final stage B ----------
__global__ __launch_bounds__(64) void k_reduce(const float* __restrict__ fpart, const float* __restrict__ bc,
                                               float* __restrict__ out, int nb) {
    if (threadIdx.x == 0) {
        float s = 0.f;
        for (int q = 0; q < nb; q++) s += fpart[q];
        out[0] = s + bc[0];
    }
}

// ---------- sentinel if workspace too small ----------
__global__ void k_sentinel(float* out) { out[0] = 12345.0f; }

extern "C" void kernel_launch(void* const* d_in, const int* in_sizes, int n_in,
                              void* d_out, int out_size, void* d_ws, size_t ws_size,
                              hipStream_t stream) {
    const float* ns   = (const float*)d_in[0];
    const int*   src  = (const int*)d_in[1];
    const int*   dst  = (const int*)d_in[2];
    const float* Wpre = (const float*)d_in[3];
    const float* bpre = (const float*)d_in[4];
    const float* kern = (const float*)d_in[5];
    const float* att  = (const float*)d_in[6];
    const float* Wl   = (const float*)d_in[7];
    const float* bl   = (const float*)d_in[8];
    const float* Wc   = (const float*)d_in[9];
    const float* bc   = (const float*)d_in[10];
    int n = in_sizes[9];   // Wc has n elements
    int E = in_sizes[1];

    size_t need = 0;
    auto sz = [&](size_t bytes) { size_t o = need; need += (bytes + 255) & ~255ull; return o; };
    size_t o_xh    = sz((size_t)n * D * 2);          // bf16 hi plane of x
    size_t o_xl    = sz((size_t)n * D * 2);          // bf16 lo plane of x
    size_t o_Ht    = sz((size_t)n * D * 2);          // bf16 Ht, node-major [n][800]
    size_t o_bsp   = sz(3ull * D * D * 2);           // bf16 transposed weights (hi only)
    size_t o_s     = sz((size_t)n * 8 * 4);          // [n][8]
    size_t o_t     = sz((size_t)n * 8 * 4);          // [n][8]
    size_t o_rp    = sz(((size_t)n + 1) * 4);
    size_t o_fp    = sz(128 * 4);

    if (need > ws_size) {   // diagnostic: absmax will be ~12345
        k_sentinel<<<1, 1, 0, stream>>>((float*)d_out);
        return;
    }

    char* ws = (char*)d_ws;
    ushort* xh    = (ushort*)(ws + o_xh);
    ushort* xl    = (ushort*)(ws + o_xl);
    ushort* Ht    = (ushort*)(ws + o_Ht);
    ushort* bsp   = (ushort*)(ws + o_bsp);
    float*  s_all = (float*)(ws + o_s);
    float*  t_all = (float*)(ws + o_t);
    int*    row_ptr = (int*)(ws + o_rp);
    float*  fpart = (float*)(ws + o_fp);

    k_rowptr<<<(n + 1 + 255) / 256, 256, 0, stream>>>(src, E, n, row_ptr);
    k_repack<<<(3 * D * D + 255) / 256, 256, 0, stream>>>(kern, bsp);
    dim3 gpre((D + 255) / 256, (n + 31) / 32);
    k_pre<<<gpre, 256, 0, stream>>>(ns, Wpre, bpre, xh, xl, n);

    int nrb = (n + 127) / 128;                    // 391 row blocks
    int grid_g = 8 * (((nrb + 7) / 8) * 5);       // swizzle-decoded inside kernel
    for (int l = 0; l < 3; l++) {
        hipMemsetAsync(s_all, 0, (size_t)n * 8 * 4, stream);
        hipMemsetAsync(t_all, 0, (size_t)n * 8 * 4, stream);
        k_gemm<<<grid_g, 256, 0, stream>>>(xh, xl, bsp + (size_t)l * D * D,
                                           att + l * HEADS * 2 * HIDDEN, Ht, s_all, t_all, n);
        k_edge<<<n, 256, 0, stream>>>(Ht, xh, xl, s_all, t_all, dst, row_ptr, n);
    }

    k_final<<<120, 256, 0, stream>>>(xh, xl, Wl, bl, Wc, fpart, n);
    k_reduce<<<1, 64, 0, stream>>>(fpart, bc, (float*)d_out, 120);
}

// Round 12
// 1293.477 us; speedup vs baseline: 1.2608x; 1.2608x over previous
//
#include <hip/hip_runtime.h>
#include <math.h>

#define HIDDEN 100
#define HEADS 8
#define D 800          // HIDDEN*HEADS
#define ALPHA 0.2f

typedef unsigned short ushort;
typedef unsigned int uint;
typedef __attribute__((ext_vector_type(8))) _Float16 f16x8;
typedef __attribute__((ext_vector_type(4))) float f32x4;

__device__ inline float h2f(ushort u) { union { ushort s; _Float16 h; } v; v.s = u; return (float)v.h; }
__device__ inline ushort f2h(float f) { union { ushort s; _Float16 h; } v; v.h = (_Float16)f; return v.s; }

// async global->LDS, 16B per lane; LDS dest must be the WAVE-UNIFORM base (HW adds lane*16)
__device__ inline void gl_lds16(const void* g, void* l) {
    __builtin_amdgcn_global_load_lds((const __attribute__((address_space(1))) void*)g,
                                     (__attribute__((address_space(3))) void*)l, 16, 0, 0);
}

// ---------- CSR row_ptr from sorted src via binary search ----------
__global__ void k_rowptr(const int* __restrict__ src, int E, int n, int* __restrict__ row_ptr) {
    int i = blockIdx.x * blockDim.x + threadIdx.x;
    if (i > n) return;
    int lo = 0, hi = E;
    while (lo < hi) { int mid = (lo + hi) >> 1; if (src[mid] < i) lo = mid + 1; else hi = mid; }
    row_ptr[i] = lo;
}

// ---------- repack kernels (3,8,800,100) -> per-layer transposed f16 ----------
// Bsp layout: [layer][n=800][k=800] f16, Bt[n][k] = kin[l, n/100, k, n%100]
__global__ void k_repack(const float* __restrict__ kin, ushort* __restrict__ bsp) {
    int gid = blockIdx.x * blockDim.x + threadIdx.x;
    if (gid >= 3 * D * D) return;
    int l = gid / (D * D);
    int rem = gid % (D * D);
    int nn = rem / D;        // output col (n)
    int k = rem % D;         // output row in k
    int h = nn / HIDDEN, c = nn % HIDDEN;
    float v = kin[((size_t)(l * HEADS + h) * D + k) * HIDDEN + c];
    bsp[((size_t)l * D + nn) * D + k] = f2h(v);
}

// ---------- x = relu(ns @ W_pre + b_pre), K=32; output single f16 plane ----------
__global__ __launch_bounds__(256) void k_pre(const float* __restrict__ ns, const float* __restrict__ W,
                                             const float* __restrict__ b, ushort* __restrict__ xf, int n) {
    int j = blockIdx.x * 256 + threadIdx.x;
    if (j >= D) return;
    float wk[32];
#pragma unroll
    for (int k = 0; k < 32; k++) wk[k] = W[k * D + j];
    float bj = b[j];
    int r0 = blockIdx.y * 32;
    int r1 = min(r0 + 32, n);
    for (int r = r0; r < r1; r++) {
        float acc = bj;
#pragma unroll
        for (int k = 0; k < 32; k++) acc += ns[r * 32 + k] * wk[k];
        xf[(size_t)r * D + j] = f2h(fmaxf(acc, 0.f));
    }
}

// ---------- Ht[M x 800](f16) = xf[M x 800](f16) @ Bsp[800 x 800](f16), single-pass f16 MFMA ----------
// BM=128 BN=160 BK=32; 4 waves (2x2); dbuf LDS 36KB (4 blocks/CU); all staging via
// global_load_lds; counted-vmcnt pipeline; XCD-aware block swizzle.
__global__ __launch_bounds__(256) void k_gemm(const ushort* __restrict__ xf, const ushort* __restrict__ Bsp,
                                              ushort* __restrict__ C, int M) {
    // single fragment-ordered LDS: tiles 0..7 = A (rows), 8..17 = B (cols); 1KB per 16x32 tile
    __shared__ __align__(16) ushort Sf[2][18 * 512];   // 36 KB

    int d = blockIdx.x;
    int q = d & 7, m = d >> 3;      // XCD swizzle: same row-block -> same XCD
    int c = m % 5, j = m / 5;
    int r = j * 8 + q;
    int nrb = (M + 127) >> 7;
    if (r >= nrb) return;
    int row0 = r * 128, col0 = c * 160;

    int t = threadIdx.x;
    int w = t >> 6, lane = t & 63;
    int wr = w >> 1, wc = w & 1;
    int l15 = lane & 15, ks = lane >> 4;

    // 18 loads: idx 0..7 A-tiles, 8..17 B-tiles; wave w handles idx%4==w -> cnt {5,5,4,4}
    int cnt = (w < 2) ? 5 : 4;
    const ushort* srcs[5];
    uint ldso[5];
    {
        int c2 = 0;
        for (int idx = w; idx < 18; idx += 4, c2++) {
            if (idx < 8) {
                int row = min(row0 + idx * 16 + l15, M - 1);
                srcs[c2] = xf + (size_t)row * D + ks * 8;
            } else {
                int col = col0 + (idx - 8) * 16 + l15;
                srcs[c2] = Bsp + (size_t)col * D + ks * 8;
            }
            ldso[c2] = idx * 512;
        }
    }

    f32x4 acc[4][5] = {};

    auto stage = [&](int buf, int k0) {
        for (int i = 0; i < cnt; i++) gl_lds16(srcs[i] + k0, &Sf[buf][ldso[i]]);
    };
    auto compute = [&](int buf) {
        f16x8 bh[5];
#pragma unroll
        for (int ni = 0; ni < 5; ni++)
            bh[ni] = *(const f16x8*)&Sf[buf][(8 + wc * 5 + ni) * 512 + lane * 8];
#pragma unroll
        for (int mi = 0; mi < 4; mi++) {
            f16x8 ah = *(const f16x8*)&Sf[buf][(wr * 4 + mi) * 512 + lane * 8];
#pragma unroll
            for (int ni = 0; ni < 5; ni++)
                acc[mi][ni] = __builtin_amdgcn_mfma_f32_16x16x32_f16(ah, bh[ni], acc[mi][ni], 0, 0, 0);
        }
    };

    stage(0, 0);                               // S_0 in flight
    for (int kt = 0; kt < 25; kt++) {
        if (kt < 24) {
            stage((kt + 1) & 1, (kt + 1) * 32);   // S_{t+1} stays in flight across the barrier
            if (w < 2) asm volatile("s_waitcnt vmcnt(5)" ::: "memory");
            else       asm volatile("s_waitcnt vmcnt(4)" ::: "memory");
        } else {
            asm volatile("s_waitcnt vmcnt(0)" ::: "memory");
        }
        __builtin_amdgcn_s_barrier();          // all waves' S_t landed (raw barrier, no drain)
        compute(kt & 1);
        __builtin_amdgcn_s_barrier();          // all waves done reading buf before re-stage
    }

    // C/D layout: col = lane&15, row = (lane>>4)*4 + reg   [m89-verified]
#pragma unroll
    for (int mi = 0; mi < 4; mi++) {
#pragma unroll
        for (int ni = 0; ni < 5; ni++) {
            int gr0 = row0 + wr * 64 + mi * 16 + ks * 4;
            int gc = col0 + wc * 80 + ni * 16 + l15;
#pragma unroll
            for (int rr = 0; rr < 4; rr++) {
                int gr = gr0 + rr;
                if (gr < M) C[(size_t)gr * D + gc] = f2h(acc[mi][ni][rr]);
            }
        }
    }
}

// ---------- s,t per (node, head) from f16 Ht ----------
__global__ __launch_bounds__(256) void k_st(const ushort* __restrict__ Ht, const float* __restrict__ att_l,
                                            float* __restrict__ s_all, float* __restrict__ t_all, int n) {
    int gid = blockIdx.x * blockDim.x + threadIdx.x;
    if (gid >= n * HEADS) return;
    int i = gid >> 3, h = gid & 7;
    const uint2* hp2 = (const uint2*)(Ht + (size_t)i * D + h * HIDDEN);
    const float* As = att_l + h * 2 * HIDDEN;
    const float* At = As + HIDDEN;
    float s = 0.f, t = 0.f;
#pragma unroll 5
    for (int q = 0; q < 25; q++) {
        uint2 v = hp2[q];
        float f0 = h2f((ushort)(v.x & 0xFFFF)), f1 = h2f((ushort)(v.x >> 16));
        float f2 = h2f((ushort)(v.y & 0xFFFF)), f3 = h2f((ushort)(v.y >> 16));
        int c = q * 4;
        s += f0 * As[c] + f1 * As[c + 1] + f2 * As[c + 2] + f3 * As[c + 3];
        t += f0 * At[c] + f1 * At[c + 1] + f2 * At[c + 2] + f3 * At[c + 3];
    }
    s_all[gid] = s;
    t_all[gid] = t;
}

// ---------- per-node segment softmax + aggregate + relu + residual (x f16 in-place) ----------
__global__ __launch_bounds__(256) void k_edge(const ushort* __restrict__ Ht, ushort* __restrict__ xf,
                                              const float* __restrict__ s_all, const float* __restrict__ t_all,
                                              const int* __restrict__ dst, const int* __restrict__ row_ptr,
                                              int n) {
    int i = blockIdx.x;
    int t = threadIdx.x;
    __shared__ float lw[32][8];
    __shared__ int ld[32];
    int e0 = row_ptr[i], e1 = row_ptr[i + 1];
    int h = t / 25;            // head for aggregation (valid for t<200)
    int el = t >> 3, hh = t & 7;
    float s_ih = s_all[i * 8 + hh];
    float acc0 = 0, acc1 = 0, acc2 = 0, acc3 = 0, den = 0;

    for (int base = e0; base < e1; base += 32) {
        int cnt = min(32, e1 - base);
        __syncthreads();
        if (el < cnt) {
            int dd = dst[base + el];
            float ev = s_ih + t_all[dd * 8 + hh];
            ev = ev >= 0.f ? ev : ALPHA * ev;
            ev = fminf(fmaxf(ev, -2.f), 2.f);
            lw[el][hh] = __expf(ev);
            if (hh == 0) ld[el] = dd;
        }
        __syncthreads();
        if (t < 200) {
#pragma unroll 4
            for (int e = 0; e < cnt; e++) {
                int dd = ld[e];
                uint2 v = *(const uint2*)(Ht + (size_t)dd * D + t * 4);
                float wgt = lw[e][h];
                acc0 += wgt * h2f((ushort)(v.x & 0xFFFF));
                acc1 += wgt * h2f((ushort)(v.x >> 16));
                acc2 += wgt * h2f((ushort)(v.y & 0xFFFF));
                acc3 += wgt * h2f((ushort)(v.y >> 16));
                den += wgt;
            }
        }
    }
    if (t < 200) {
        size_t off = (size_t)i * D + t * 4;
        uint2 vx = *(uint2*)(xf + off);
        float x0 = h2f((ushort)(vx.x & 0xFFFF));
        float x1 = h2f((ushort)(vx.x >> 16));
        float x2 = h2f((ushort)(vx.y & 0xFFFF));
        float x3 = h2f((ushort)(vx.y >> 16));
        float inv = den > 0.f ? 1.f / den : 0.f;
        x0 += fmaxf(acc0 * inv, 0.f);
        x1 += fmaxf(acc1 * inv, 0.f);
        x2 += fmaxf(acc2 * inv, 0.f);
        x3 += fmaxf(acc3 * inv, 0.f);
        *(uint2*)(xf + off) = make_uint2((uint)f2h(x0) | ((uint)f2h(x1) << 16),
                                         (uint)f2h(x2) | ((uint)f2h(x3) << 16));
    }
}

// ---------- final stage A: per-block partial of sum_i (x_i . Wl + bl) * Wc_i ----------
__global__ __launch_bounds__(256) void k_final(const ushort* __restrict__ xf, const float* __restrict__ Wl,
                                               const float* __restrict__ bl, const float* __restrict__ Wc,
                                               float* __restrict__ fpart, int n) {
    __shared__ float part[4];
    int lane = threadIdx.x & 63, w = threadIdx.x >> 6;
    int wid = blockIdx.x * 4 + w;
    int nw = gridDim.x * 4;
    float p = 0.f;
    for (int i = wid; i < n; i += nw) {
        float dot = 0.f;
#pragma unroll
        for (int r = 0; r < 13; r++) {
            int j = r * 64 + lane;
            if (j < D) dot += h2f(xf[(size_t)i * D + j]) * Wl[j];
        }
#pragma unroll
        for (int off = 32; off; off >>= 1) dot += __shfl_xor(dot, off);
        if (lane == 0) p += (dot + bl[0]) * Wc[i];
    }
    if (lane == 0) part[w] = p;
    __syncthreads();
    if (threadIdx.x == 0) fpart[blockIdx.x] = part[0] + part[1] + part[2] + part[3];
}

// ---------- final stage B ----------
__global__ __launch_bounds__(64) void k_reduce(const float* __restrict__ fpart, const float* __restrict__ bc,
                                               float* __restrict__ out, int nb) {
    if (threadIdx.x == 0) {
        float s = 0.f;
        for (int q = 0; q < nb; q++) s += fpart[q];
        out[0] = s + bc[0];
    }
}

// ---------- sentinel if workspace too small ----------
__global__ void k_sentinel(float* out) { out[0] = 12345.0f; }

extern "C" void kernel_launch(void* const* d_in, const int* in_sizes, int n_in,
                              void* d_out, int out_size, void* d_ws, size_t ws_size,
                              hipStream_t stream) {
    const float* ns   = (const float*)d_in[0];
    const int*   src  = (const int*)d_in[1];
    const int*   dst  = (const int*)d_in[2];
    const float* Wpre = (const float*)d_in[3];
    const float* bpre = (const float*)d_in[4];
    const float* kern = (const float*)d_in[5];
    const float* att  = (const float*)d_in[6];
    const float* Wl   = (const float*)d_in[7];
    const float* bl   = (const float*)d_in[8];
    const float* Wc   = (const float*)d_in[9];
    const float* bc   = (const float*)d_in[10];
    int n = in_sizes[9];   // Wc has n elements
    int E = in_sizes[1];

    size_t need = 0;
    auto sz = [&](size_t bytes) { size_t o = need; need += (bytes + 255) & ~255ull; return o; };
    size_t o_xf    = sz((size_t)n * D * 2);          // f16 x plane (in-place across layers)
    size_t o_Ht    = sz((size_t)n * D * 2);          // f16 Ht
    size_t o_bsp   = sz(3ull * D * D * 2);           // f16 transposed weights
    size_t o_s     = sz((size_t)n * 8 * 4);
    size_t o_t     = sz((size_t)n * 8 * 4);
    size_t o_rp    = sz(((size_t)n + 1) * 4);
    size_t o_fp    = sz(128 * 4);

    if (need > ws_size) {   // diagnostic: absmax will be ~12345
        k_sentinel<<<1, 1, 0, stream>>>((float*)d_out);
        return;
    }

    char* ws = (char*)d_ws;
    ushort* xf    = (ushort*)(ws + o_xf);
    ushort* Ht    = (ushort*)(ws + o_Ht);
    ushort* bsp   = (ushort*)(ws + o_bsp);
    float*  s_all = (float*)(ws + o_s);
    float*  t_all = (float*)(ws + o_t);
    int*    row_ptr = (int*)(ws + o_rp);
    float*  fpart = (float*)(ws + o_fp);

    k_rowptr<<<(n + 1 + 255) / 256, 256, 0, stream>>>(src, E, n, row_ptr);
    k_repack<<<(3 * D * D + 255) / 256, 256, 0, stream>>>(kern, bsp);
    dim3 gpre((D + 255) / 256, (n + 31) / 32);
    k_pre<<<gpre, 256, 0, stream>>>(ns, Wpre, bpre, xf, n);

    int nrb = (n + 127) / 128;                    // 391 row blocks
    int grid_g = 8 * (((nrb + 7) / 8) * 5);       // swizzle-decoded inside kernel
    for (int l = 0; l < 3; l++) {
        k_gemm<<<grid_g, 256, 0, stream>>>(xf, bsp + (size_t)l * D * D, Ht, n);
        k_st<<<(n * HEADS + 255) / 256, 256, 0, stream>>>(Ht, att + l * HEADS * 2 * HIDDEN, s_all, t_all, n);
        k_edge<<<n, 256, 0, stream>>>(Ht, xf, s_all, t_all, dst, row_ptr, n);
    }

    k_final<<<120, 256, 0, stream>>>(xf, Wl, bl, Wc, fpart, n);
    k_reduce<<<1, 64, 0, stream>>>(fpart, bc, (float*)d_out, 120);
}